// Round 8
// baseline (793.612 us; speedup 1.0000x reference)
//
#include <hip/hip_runtime.h>
#include <hip/hip_bf16.h>

typedef _Float16 f16;
typedef f16   f16x8 __attribute__((ext_vector_type(8)));
typedef float f32x4 __attribute__((ext_vector_type(4)));

#define HW 36864      /* 192*192 */
#define TS 9437184    /* 256*36864 : per-plane per-batch elements */

// ---------------------------------------------------------------------------
// Pre-kernel: W (fp32 256x256) -> 3 fp16 planes: Wq, Wk, Wv
// ---------------------------------------------------------------------------
__global__ __launch_bounds__(256) void convert_w_kernel(
    const float* __restrict__ wq, const float* __restrict__ wk,
    const float* __restrict__ wv, f16* __restrict__ wp) {
  int i = blockIdx.x * 256 + threadIdx.x;  // 0 .. 65535
  wp[i]             = (f16)wq[i];
  wp[65536 + i]     = (f16)wk[i];
  wp[2 * 65536 + i] = (f16)wv[i];
}

// ---------------------------------------------------------------------------
// Stage 1: 1x1 conv GEMM  out[o,n] = sum_i W[o,i] x[i,n] + b[o]
// Single-pass fp16 (fp32 accumulate). grid = (576, 3), block = 256.
// ---------------------------------------------------------------------------
__global__ __launch_bounds__(256) void conv1x1_kernel(
    const float* __restrict__ xq, const float* __restrict__ xk, const float* __restrict__ xv,
    const f16* __restrict__ wp,
    const float* __restrict__ bq, const float* __restrict__ bk, const float* __restrict__ bv,
    f16* __restrict__ qkv) {
  const int t = blockIdx.y;
  const float* __restrict__ in   = (t == 0) ? xq : (t == 1 ? xk : xv);
  const float* __restrict__ bias = (t == 0) ? bq : (t == 1 ? bk : bv);
  const f16* __restrict__ W = wp + t * 65536;
  f16* __restrict__ outp    = qkv + (size_t)t * TS;

  const int n0  = blockIdx.x * 64;
  const int tid = threadIdx.x;
  const int l   = tid & 63;
  const int wv  = tid >> 6;
  const int lr  = l & 15, lg = l >> 4;

  __shared__ f16 Xt[64][264];   // [n][i], +8 pad

#pragma unroll
  for (int it = 0; it < 8; ++it) {
    const int ib = it * 32 + wv * 8;
    float v[8];
#pragma unroll
    for (int j = 0; j < 8; ++j) v[j] = in[(size_t)(ib + j) * HW + n0 + l];
    union { f16 h[8]; f16x8 vec; } u;
#pragma unroll
    for (int j = 0; j < 8; ++j) u.h[j] = (f16)v[j];
    *(f16x8*)&Xt[l][ib] = u.vec;
  }
  __syncthreads();

  f32x4 acc[4][4];
#pragma unroll
  for (int fo = 0; fo < 4; ++fo)
#pragma unroll
    for (int fn = 0; fn < 4; ++fn) acc[fo][fn] = (f32x4){0.f, 0.f, 0.f, 0.f};

  const int obase = wv * 64;
#pragma unroll
  for (int ks = 0; ks < 8; ++ks) {
    f16x8 aw[4], bx[4];
#pragma unroll
    for (int fo = 0; fo < 4; ++fo)
      aw[fo] = *(const f16x8*)(W + (obase + fo * 16 + lr) * 256 + ks * 32 + lg * 8);
#pragma unroll
    for (int fn = 0; fn < 4; ++fn)
      bx[fn] = *(const f16x8*)&Xt[lr + 16 * fn][ks * 32 + lg * 8];
#pragma unroll
    for (int fo = 0; fo < 4; ++fo)
#pragma unroll
      for (int fn = 0; fn < 4; ++fn)
        acc[fo][fn] = __builtin_amdgcn_mfma_f32_16x16x32_f16(aw[fo], bx[fn], acc[fo][fn], 0, 0, 0);
  }

  // epilogue: C layout col n = lane&15, row o = 4*(lane>>4)+reg
#pragma unroll
  for (int fo = 0; fo < 4; ++fo) {
    const int orow = obase + fo * 16 + lg * 4;
    float bz[4];
#pragma unroll
    for (int r = 0; r < 4; ++r) bz[r] = bias[orow + r];
#pragma unroll
    for (int fn = 0; fn < 4; ++fn)
#pragma unroll
      for (int r = 0; r < 4; ++r)
        outp[(size_t)(orow + r) * HW + n0 + 16 * fn + lr] = (f16)(acc[fo][fn][r] + bz[r]);
  }
}

// ---------------------------------------------------------------------------
// Stage 2: attention, 2 blocks per channel (grid 512), 384 threads (6 waves).
// LDS 76.5 KB -> 2 blocks/CU: anti-phased blocks cover each other's staging
// (R6/R7 lockstep 1-block/CU left the phase chain latency fully exposed).
// Block rb handles q-rows [rb*96, rb*96+96). K streamed in two 96-row panels
// (exact softmax: full S kept in regs). V^T streamed in two g-panels with
// T14 register prefetch (issue early / ds_write late).
// ---------------------------------------------------------------------------
__global__ __launch_bounds__(384, 3) void attn_kernel(
    const f16* __restrict__ qkv, float* __restrict__ outb) {
  const int bid = blockIdx.x;
  const int c   = bid >> 1;
  const int rb  = bid & 1;
  const int tid = threadIdx.x;
  const int l   = tid & 63;
  const int wv  = tid >> 6;          // 0..5
  const int lr  = l & 15, lg = l >> 4;

  const f16* __restrict__ q = qkv + (size_t)c * HW;
  const f16* __restrict__ k = qkv + (size_t)TS + (size_t)c * HW;
  const f16* __restrict__ v = qkv + 2 * (size_t)TS + (size_t)c * HW;
  float* __restrict__ outc = outb + (size_t)c * HW;

  __shared__ f16 bufA[192 * 104];            // K-panel [96][200] / V^T [192][104]
  __shared__ f16 Pf[96][200];                // normalized P rows (this block's 96)
  f16 (*KP)[200] = (f16 (*)[200])bufA;
  f16 (*Vt)[104] = (f16 (*)[104])bufA;

  const int h0g = rb * 96 + wv * 16;         // global q-row base of this wave
  const int h0l = wv * 16;                   // local row base (Pf)

  // hoisted Q fragments (global, independent of LDS)
  f16x8 aq[6];
#pragma unroll
  for (int ks = 0; ks < 6; ++ks)
    aq[ks] = *(const f16x8*)(q + (h0g + lr) * 192 + ks * 32 + lg * 8);

  // ---- stage K panel 0 (rows 0..95)
#pragma unroll
  for (int jj = 0; jj < 6; ++jj) {
    int id = tid + jj * 384;                 // 2304 chunks
    int g = id / 24, wo = id % 24;
    *(f16x8*)&KP[g][wo * 8] = *(const f16x8*)(k + g * 192 + wo * 8);
  }
  __syncthreads();

  f32x4 S[12];
#pragma unroll
  for (int fg = 0; fg < 12; ++fg) S[fg] = (f32x4){0.f, 0.f, 0.f, 0.f};

  // S part 1: g in [0,96)
#pragma unroll
  for (int ks = 0; ks < 6; ++ks)
#pragma unroll
    for (int fg = 0; fg < 6; ++fg) {
      f16x8 bk_ = *(const f16x8*)&KP[16 * fg + lr][ks * 32 + lg * 8];
      S[fg] = __builtin_amdgcn_mfma_f32_16x16x32_f16(aq[ks], bk_, S[fg], 0, 0, 0);
    }
  __syncthreads();                            // panel-0 reads done

  // ---- stage K panel 1 (rows 96..191)
#pragma unroll
  for (int jj = 0; jj < 6; ++jj) {
    int id = tid + jj * 384;
    int g = id / 24, wo = id % 24;
    *(f16x8*)&KP[g][wo * 8] = *(const f16x8*)(k + (96 + g) * 192 + wo * 8);
  }

  // T14: prefetch V half-0 into regs (consumed after softmax barrier)
  const int jA = tid;                         // job A (always)
  const int gA = (jA % 12) * 8, wA = (jA / 12) * 4;
  const int jB = tid + 384;                   // job B (waves 0..2 only)
  const int gB = (jB % 12) * 8, wB = (jB / 12) * 4;
  uint2 vpA[8], vpB[8];
#pragma unroll
  for (int j = 0; j < 8; ++j) vpA[j] = *(const uint2*)(v + (gA + j) * 192 + wA);
  if (tid < 192) {
#pragma unroll
    for (int j = 0; j < 8; ++j) vpB[j] = *(const uint2*)(v + (gB + j) * 192 + wB);
  }
  __syncthreads();                            // panel-1 visible

  // S part 2: g in [96,192)
#pragma unroll
  for (int ks = 0; ks < 6; ++ks)
#pragma unroll
    for (int fg = 0; fg < 6; ++fg) {
      f16x8 bk_ = *(const f16x8*)&KP[16 * fg + lr][ks * 32 + lg * 8];
      S[6 + fg] = __builtin_amdgcn_mfma_f32_16x16x32_f16(aq[ks], bk_, S[6 + fg], 0, 0, 0);
    }

  // exact softmax per row (row = 4*lg + r), normalized P -> Pf (wave-private rows)
#pragma unroll
  for (int r = 0; r < 4; ++r) {
    float m = S[0][r];
#pragma unroll
    for (int fg = 1; fg < 12; ++fg) m = fmaxf(m, S[fg][r]);
    m = fmaxf(m, __shfl_xor(m, 1));
    m = fmaxf(m, __shfl_xor(m, 2));
    m = fmaxf(m, __shfl_xor(m, 4));
    m = fmaxf(m, __shfl_xor(m, 8));
    float s = 0.f;
#pragma unroll
    for (int fg = 0; fg < 12; ++fg) {
      float e = __expf(S[fg][r] - m);
      S[fg][r] = e;
      s += e;
    }
    s += __shfl_xor(s, 1);
    s += __shfl_xor(s, 2);
    s += __shfl_xor(s, 4);
    s += __shfl_xor(s, 8);
    float rs = 1.f / s;
#pragma unroll
    for (int fg = 0; fg < 12; ++fg)
      Pf[h0l + lg * 4 + r][16 * fg + lr] = (f16)(S[fg][r] * rs);
  }
  __syncthreads();                            // KP reads done -> reuse as Vt

  // ---- write V^T half-0 from prefetched regs
  {
#pragma unroll
    for (int qd = 0; qd < 4; ++qd) {
      union { unsigned short s[8]; f16x8 vec; } u;
#pragma unroll
      for (int j = 0; j < 8; ++j) u.s[j] = ((const unsigned short*)&vpA[j])[qd];
      *(f16x8*)&Vt[wA + qd][gA] = u.vec;
    }
    if (tid < 192) {
#pragma unroll
      for (int qd = 0; qd < 4; ++qd) {
        union { unsigned short s[8]; f16x8 vec; } u;
#pragma unroll
        for (int j = 0; j < 8; ++j) u.s[j] = ((const unsigned short*)&vpB[j])[qd];
        *(f16x8*)&Vt[wB + qd][gB] = u.vec;
      }
    }
  }

  // T14: prefetch V half-1 (consumed after PV half-0)
#pragma unroll
  for (int j = 0; j < 8; ++j) vpA[j] = *(const uint2*)(v + (96 + gA + j) * 192 + wA);
  if (tid < 192) {
#pragma unroll
    for (int j = 0; j < 8; ++j) vpB[j] = *(const uint2*)(v + (96 + gB + j) * 192 + wB);
  }
  __syncthreads();                            // Vt half-0 visible

  f32x4 O[12];
#pragma unroll
  for (int fn = 0; fn < 12; ++fn) O[fn] = (f32x4){0.f, 0.f, 0.f, 0.f};

  // PV half-0: g in [0,96)
#pragma unroll
  for (int ks = 0; ks < 3; ++ks) {
    f16x8 pa = *(const f16x8*)&Pf[h0l + lr][ks * 32 + lg * 8];
#pragma unroll
    for (int fn = 0; fn < 12; ++fn) {
      f16x8 bv_ = *(const f16x8*)&Vt[16 * fn + lr][ks * 32 + lg * 8];
      O[fn] = __builtin_amdgcn_mfma_f32_16x16x32_f16(pa, bv_, O[fn], 0, 0, 0);
    }
  }
  __syncthreads();                            // Vt half-0 reads done

  // ---- write V^T half-1
  {
#pragma unroll
    for (int qd = 0; qd < 4; ++qd) {
      union { unsigned short s[8]; f16x8 vec; } u;
#pragma unroll
      for (int j = 0; j < 8; ++j) u.s[j] = ((const unsigned short*)&vpA[j])[qd];
      *(f16x8*)&Vt[wA + qd][gA] = u.vec;
    }
    if (tid < 192) {
#pragma unroll
      for (int qd = 0; qd < 4; ++qd) {
        union { unsigned short s[8]; f16x8 vec; } u;
#pragma unroll
        for (int j = 0; j < 8; ++j) u.s[j] = ((const unsigned short*)&vpB[j])[qd];
        *(f16x8*)&Vt[wB + qd][gB] = u.vec;
      }
    }
  }
  __syncthreads();                            // Vt half-1 visible

  // PV half-1: g in [96,192)
#pragma unroll
  for (int ks = 3; ks < 6; ++ks) {
    f16x8 pa = *(const f16x8*)&Pf[h0l + lr][ks * 32 + lg * 8];
#pragma unroll
    for (int fn = 0; fn < 12; ++fn) {
      f16x8 bv_ = *(const f16x8*)&Vt[16 * fn + lr][(ks - 3) * 32 + lg * 8];
      O[fn] = __builtin_amdgcn_mfma_f32_16x16x32_f16(pa, bv_, O[fn], 0, 0, 0);
    }
  }

#pragma unroll
  for (int fn = 0; fn < 12; ++fn)
#pragma unroll
    for (int r = 0; r < 4; ++r)
      outc[(size_t)(h0g + lg * 4 + r) * 192 + 16 * fn + lr] = O[fn][r];
}

// ---------------------------------------------------------------------------
extern "C" void kernel_launch(void* const* d_in, const int* in_sizes, int n_in,
                              void* d_out, int out_size, void* d_ws, size_t ws_size,
                              hipStream_t stream) {
  const float* query = (const float*)d_in[0];
  const float* key_  = (const float*)d_in[1];
  const float* value = (const float*)d_in[2];
  const float* Wq    = (const float*)d_in[3];
  const float* bq    = (const float*)d_in[4];
  const float* Wk    = (const float*)d_in[5];
  const float* bk    = (const float*)d_in[6];
  const float* Wv    = (const float*)d_in[7];
  const float* bv    = (const float*)d_in[8];
  float* out = (float*)d_out;

  f16* wp  = (f16*)d_ws;                        // 3*65536 fp16 = 384 KB
  f16* qkv = (f16*)((char*)d_ws + 524288);      // 3*TS fp16 = 56.6 MB (per-batch, reused)

  convert_w_kernel<<<256, 256, 0, stream>>>(Wq, Wk, Wv, wp);

  for (int b = 0; b < 8; ++b) {
    const size_t off = (size_t)b * TS;
    conv1x1_kernel<<<dim3(576, 3), 256, 0, stream>>>(
        query + off, key_ + off, value + off, wp, bq, bk, bv, qkv);
    attn_kernel<<<512, 384, 0, stream>>>(qkv, out + off);
  }
}

// Round 9
// 723.105 us; speedup vs baseline: 1.0975x; 1.0975x over previous
//
#include <hip/hip_runtime.h>
#include <hip/hip_bf16.h>

typedef _Float16 f16;
typedef f16   f16x8 __attribute__((ext_vector_type(8)));
typedef float f32x4 __attribute__((ext_vector_type(4)));

#define HW 36864      /* 192*192 */
#define TS 9437184    /* 256*36864 : per-plane per-batch elements */

// ---------------------------------------------------------------------------
// Pre-kernel: W (fp32 256x256) -> 3 fp16 planes: Wq, Wk, Wv
// ---------------------------------------------------------------------------
__global__ __launch_bounds__(256) void convert_w_kernel(
    const float* __restrict__ wq, const float* __restrict__ wk,
    const float* __restrict__ wv, f16* __restrict__ wp) {
  int i = blockIdx.x * 256 + threadIdx.x;  // 0 .. 65535
  wp[i]             = (f16)wq[i];
  wp[65536 + i]     = (f16)wk[i];
  wp[2 * 65536 + i] = (f16)wv[i];
}

// ---------------------------------------------------------------------------
// Stage 1: 1x1 conv GEMM  out[o,n] = sum_i W[o,i] x[i,n] + b[o]
// Single-pass fp16 (fp32 accumulate). grid = (576, 3), block = 256.
// ---------------------------------------------------------------------------
__global__ __launch_bounds__(256) void conv1x1_kernel(
    const float* __restrict__ xq, const float* __restrict__ xk, const float* __restrict__ xv,
    const f16* __restrict__ wp,
    const float* __restrict__ bq, const float* __restrict__ bk, const float* __restrict__ bv,
    f16* __restrict__ qkv) {
  const int t = blockIdx.y;
  const float* __restrict__ in   = (t == 0) ? xq : (t == 1 ? xk : xv);
  const float* __restrict__ bias = (t == 0) ? bq : (t == 1 ? bk : bv);
  const f16* __restrict__ W = wp + t * 65536;
  f16* __restrict__ outp    = qkv + (size_t)t * TS;

  const int n0  = blockIdx.x * 64;
  const int tid = threadIdx.x;
  const int l   = tid & 63;
  const int wv  = tid >> 6;
  const int lr  = l & 15, lg = l >> 4;

  __shared__ f16 Xt[64][264];   // [n][i], +8 pad

#pragma unroll
  for (int it = 0; it < 8; ++it) {
    const int ib = it * 32 + wv * 8;
    float v[8];
#pragma unroll
    for (int j = 0; j < 8; ++j) v[j] = in[(size_t)(ib + j) * HW + n0 + l];
    union { f16 h[8]; f16x8 vec; } u;
#pragma unroll
    for (int j = 0; j < 8; ++j) u.h[j] = (f16)v[j];
    *(f16x8*)&Xt[l][ib] = u.vec;
  }
  __syncthreads();

  f32x4 acc[4][4];
#pragma unroll
  for (int fo = 0; fo < 4; ++fo)
#pragma unroll
    for (int fn = 0; fn < 4; ++fn) acc[fo][fn] = (f32x4){0.f, 0.f, 0.f, 0.f};

  const int obase = wv * 64;
#pragma unroll
  for (int ks = 0; ks < 8; ++ks) {
    f16x8 aw[4], bx[4];
#pragma unroll
    for (int fo = 0; fo < 4; ++fo)
      aw[fo] = *(const f16x8*)(W + (obase + fo * 16 + lr) * 256 + ks * 32 + lg * 8);
#pragma unroll
    for (int fn = 0; fn < 4; ++fn)
      bx[fn] = *(const f16x8*)&Xt[lr + 16 * fn][ks * 32 + lg * 8];
#pragma unroll
    for (int fo = 0; fo < 4; ++fo)
#pragma unroll
      for (int fn = 0; fn < 4; ++fn)
        acc[fo][fn] = __builtin_amdgcn_mfma_f32_16x16x32_f16(aw[fo], bx[fn], acc[fo][fn], 0, 0, 0);
  }

  // epilogue: C layout col n = lane&15, row o = 4*(lane>>4)+reg
#pragma unroll
  for (int fo = 0; fo < 4; ++fo) {
    const int orow = obase + fo * 16 + lg * 4;
    float bz[4];
#pragma unroll
    for (int r = 0; r < 4; ++r) bz[r] = bias[orow + r];
#pragma unroll
    for (int fn = 0; fn < 4; ++fn)
#pragma unroll
      for (int r = 0; r < 4; ++r)
        outp[(size_t)(orow + r) * HW + n0 + 16 * fn + lr] = (f16)(acc[fo][fn][r] + bz[r]);
  }
}

// ---------------------------------------------------------------------------
// Stage 2: per-(b,c) attention, 768 threads (12 waves, 3/SIMD), grid 256.
// R7 structure + T14 async staging:
//  - Q fragments AND the scattered V-gather are issued at the TOP of the
//    kernel (before the K-stage barrier) into registers; their L3 latency
//    hides under K staging + QK^T + softmax.
//  - V^T LDS writes (cheap, conflict-free b128) happen after barrier 2.
// Phases: [K stage + issue aq/vp] B1 [QK^T, softmax, Pf] B2 [Vt write] B3 [PV].
// LDS = KA(76.8K) + Pf(76.8K) = 153.6 KB -> 1 block/CU. No cross-phase f32
// accumulator state -> no spill risk (~125 VGPR peak, budget 170).
// ---------------------------------------------------------------------------
__global__ __launch_bounds__(768) void attn_kernel(
    const f16* __restrict__ qkv, float* __restrict__ outb) {
  const int c   = blockIdx.x;
  const int tid = threadIdx.x;
  const int l   = tid & 63;
  const int wv  = tid >> 6;          // 0..11  == q-tile index
  const int lr  = l & 15, lg = l >> 4;

  const f16* __restrict__ q = qkv + (size_t)c * HW;
  const f16* __restrict__ k = qkv + (size_t)TS + (size_t)c * HW;
  const f16* __restrict__ v = qkv + 2 * (size_t)TS + (size_t)c * HW;
  float* __restrict__ outc = outb + (size_t)c * HW;

  __shared__ f16 KA[192][200];   // phase1: K [g][w]   phase2: V^T [w][g]
  __shared__ f16 Pf[192][200];   // normalized P [h][g]

  const int h0 = wv * 16;

  // ---- T14 issue-early: Q fragments (consumed in QK^T)
  f16x8 aq[6];
#pragma unroll
  for (int ks = 0; ks < 6; ++ks)
    aq[ks] = *(const f16x8*)(q + (h0 + lr) * 192 + ks * 32 + lg * 8);

  // ---- T14 issue-early: scattered V-gather into regs (written to LDS later)
  const int gA = (tid % 24) * 8, wA = (tid / 24) * 4;   // job A: all threads
  const int jB = tid + 768;                              // job B: tid < 384
  const int gB = (jB % 24) * 8, wB = (jB / 24) * 4;
  uint2 vpA[8], vpB[8];
#pragma unroll
  for (int j = 0; j < 8; ++j) vpA[j] = *(const uint2*)(v + (gA + j) * 192 + wA);
  if (tid < 384) {
#pragma unroll
    for (int j = 0; j < 8; ++j) vpB[j] = *(const uint2*)(v + (gB + j) * 192 + wB);
  }

  // ---- stage K -> KA (16B chunks, coalesced; 4608 = 768*6)
#pragma unroll
  for (int jj = 0; jj < 6; ++jj) {
    int id = tid + jj * 768;
    int g = id / 24, wo = id % 24;
    *(f16x8*)&KA[g][wo * 8] = *(const f16x8*)(k + g * 192 + wo * 8);
  }
  __syncthreads();                              // B1: K visible

  {
    f32x4 S[12];
#pragma unroll
    for (int fg = 0; fg < 12; ++fg) S[fg] = (f32x4){0.f, 0.f, 0.f, 0.f};
#pragma unroll
    for (int ks = 0; ks < 6; ++ks)
#pragma unroll
      for (int fg = 0; fg < 12; ++fg) {
        f16x8 bk_ = *(const f16x8*)&KA[16 * fg + lr][ks * 32 + lg * 8];
        S[fg] = __builtin_amdgcn_mfma_f32_16x16x32_f16(aq[ks], bk_, S[fg], 0, 0, 0);
      }

    // exact softmax per row (row = 4*lg + r; 16 lanes lr hold g-chunks),
    // normalize, store to Pf in [h][g] layout (C-layout-native scatter).
#pragma unroll
    for (int r = 0; r < 4; ++r) {
      float m = S[0][r];
#pragma unroll
      for (int fg = 1; fg < 12; ++fg) m = fmaxf(m, S[fg][r]);
      m = fmaxf(m, __shfl_xor(m, 1));
      m = fmaxf(m, __shfl_xor(m, 2));
      m = fmaxf(m, __shfl_xor(m, 4));
      m = fmaxf(m, __shfl_xor(m, 8));
      float s = 0.f;
#pragma unroll
      for (int fg = 0; fg < 12; ++fg) {
        float e = __expf(S[fg][r] - m);
        S[fg][r] = e;
        s += e;
      }
      s += __shfl_xor(s, 1);
      s += __shfl_xor(s, 2);
      s += __shfl_xor(s, 4);
      s += __shfl_xor(s, 8);
      float rs = 1.f / s;
#pragma unroll
      for (int fg = 0; fg < 12; ++fg)
        Pf[h0 + lg * 4 + r][16 * fg + lr] = (f16)(S[fg][r] * rs);
    }
  }
  __syncthreads();                              // B2: all KA reads done

  // ---- write V^T into KA from the preloaded regs (conflict-free b128 rows)
  {
#pragma unroll
    for (int qd = 0; qd < 4; ++qd) {
      union { unsigned short s[8]; f16x8 vec; } u;
#pragma unroll
      for (int j = 0; j < 8; ++j) u.s[j] = ((const unsigned short*)&vpA[j])[qd];
      *(f16x8*)&KA[wA + qd][gA] = u.vec;
    }
    if (tid < 384) {
#pragma unroll
      for (int qd = 0; qd < 4; ++qd) {
        union { unsigned short s[8]; f16x8 vec; } u;
#pragma unroll
        for (int j = 0; j < 8; ++j) u.s[j] = ((const unsigned short*)&vpB[j])[qd];
        *(f16x8*)&KA[wB + qd][gB] = u.vec;
      }
    }
  }
  __syncthreads();                              // B3: V^T visible

  {
    f32x4 O[12];
#pragma unroll
    for (int fn = 0; fn < 12; ++fn) O[fn] = (f32x4){0.f, 0.f, 0.f, 0.f};

#pragma unroll
    for (int ks = 0; ks < 6; ++ks) {
      f16x8 pa = *(const f16x8*)&Pf[h0 + lr][ks * 32 + lg * 8];  // A: row h, k = g
#pragma unroll
      for (int fn = 0; fn < 12; ++fn) {
        f16x8 bv_ = *(const f16x8*)&KA[16 * fn + lr][ks * 32 + lg * 8];  // B: col w, k = g
        O[fn] = __builtin_amdgcn_mfma_f32_16x16x32_f16(pa, bv_, O[fn], 0, 0, 0);
      }
    }

#pragma unroll
    for (int fn = 0; fn < 12; ++fn)
#pragma unroll
      for (int r = 0; r < 4; ++r)
        outc[(size_t)(h0 + lg * 4 + r) * 192 + 16 * fn + lr] = O[fn][r];
  }
}

// ---------------------------------------------------------------------------
extern "C" void kernel_launch(void* const* d_in, const int* in_sizes, int n_in,
                              void* d_out, int out_size, void* d_ws, size_t ws_size,
                              hipStream_t stream) {
  const float* query = (const float*)d_in[0];
  const float* key_  = (const float*)d_in[1];
  const float* value = (const float*)d_in[2];
  const float* Wq    = (const float*)d_in[3];
  const float* bq    = (const float*)d_in[4];
  const float* Wk    = (const float*)d_in[5];
  const float* bk    = (const float*)d_in[6];
  const float* Wv    = (const float*)d_in[7];
  const float* bv    = (const float*)d_in[8];
  float* out = (float*)d_out;

  f16* wp  = (f16*)d_ws;                        // 3*65536 fp16 = 384 KB
  f16* qkv = (f16*)((char*)d_ws + 524288);      // 3*TS fp16 = 56.6 MB (per-batch, reused)

  convert_w_kernel<<<256, 256, 0, stream>>>(Wq, Wk, Wv, wp);

  for (int b = 0; b < 8; ++b) {
    const size_t off = (size_t)b * TS;
    conv1x1_kernel<<<dim3(576, 3), 256, 0, stream>>>(
        query + off, key_ + off, value + off, wp, bq, bk, bv, qkv);
    attn_kernel<<<256, 768, 0, stream>>>(qkv, out + off);
  }
}

// Round 10
// 709.737 us; speedup vs baseline: 1.1182x; 1.0188x over previous
//
#include <hip/hip_runtime.h>
#include <hip/hip_bf16.h>

typedef _Float16 f16;
typedef f16   f16x8 __attribute__((ext_vector_type(8)));
typedef float f32x4 __attribute__((ext_vector_type(4)));

#define HW 36864      /* 192*192 */
#define TS 9437184    /* 256*36864 : per-plane per-batch elements */

// ---------------------------------------------------------------------------
// Pre-kernel: W (fp32 256x256) -> 3 fp16 planes: Wq, Wk, Wv
// ---------------------------------------------------------------------------
__global__ __launch_bounds__(256) void convert_w_kernel(
    const float* __restrict__ wq, const float* __restrict__ wk,
    const float* __restrict__ wv, f16* __restrict__ wp) {
  int i = blockIdx.x * 256 + threadIdx.x;  // 0 .. 65535
  wp[i]             = (f16)wq[i];
  wp[65536 + i]     = (f16)wk[i];
  wp[2 * 65536 + i] = (f16)wv[i];
}

// ---------------------------------------------------------------------------
// Stage 1: 1x1 conv GEMM  out[o,n] = sum_i W[o,i] x[i,n] + b[o]
// Single-pass fp16 (fp32 accumulate). block = 256.
// grid = (576*NB, 3): blockIdx.x = b*576 + nb  (NB = batches in this launch;
// per-batch fallback passes batch-offset pointers and grid (576,3) -> b=0).
// qkv layout: plane t of batch b at offset (b*3 + t)*TS.
// ---------------------------------------------------------------------------
__global__ __launch_bounds__(256) void conv1x1_kernel(
    const float* __restrict__ xq, const float* __restrict__ xk, const float* __restrict__ xv,
    const f16* __restrict__ wp,
    const float* __restrict__ bq, const float* __restrict__ bk, const float* __restrict__ bv,
    f16* __restrict__ qkv) {
  const int t  = blockIdx.y;
  const int b  = blockIdx.x / 576;
  const int nb = blockIdx.x % 576;
  const float* __restrict__ in   = ((t == 0) ? xq : (t == 1 ? xk : xv)) + (size_t)b * TS;
  const float* __restrict__ bias = (t == 0) ? bq : (t == 1 ? bk : bv);
  const f16* __restrict__ W = wp + t * 65536;
  f16* __restrict__ outp    = qkv + (size_t)(b * 3 + t) * TS;

  const int n0  = nb * 64;
  const int tid = threadIdx.x;
  const int l   = tid & 63;
  const int wv  = tid >> 6;
  const int lr  = l & 15, lg = l >> 4;

  __shared__ f16 Xt[64][264];   // [n][i], +8 pad

#pragma unroll
  for (int it = 0; it < 8; ++it) {
    const int ib = it * 32 + wv * 8;
    float v[8];
#pragma unroll
    for (int j = 0; j < 8; ++j) v[j] = in[(size_t)(ib + j) * HW + n0 + l];
    union { f16 h[8]; f16x8 vec; } u;
#pragma unroll
    for (int j = 0; j < 8; ++j) u.h[j] = (f16)v[j];
    *(f16x8*)&Xt[l][ib] = u.vec;
  }
  __syncthreads();

  f32x4 acc[4][4];
#pragma unroll
  for (int fo = 0; fo < 4; ++fo)
#pragma unroll
    for (int fn = 0; fn < 4; ++fn) acc[fo][fn] = (f32x4){0.f, 0.f, 0.f, 0.f};

  const int obase = wv * 64;
#pragma unroll
  for (int ks = 0; ks < 8; ++ks) {
    f16x8 aw[4], bx[4];
#pragma unroll
    for (int fo = 0; fo < 4; ++fo)
      aw[fo] = *(const f16x8*)(W + (obase + fo * 16 + lr) * 256 + ks * 32 + lg * 8);
#pragma unroll
    for (int fn = 0; fn < 4; ++fn)
      bx[fn] = *(const f16x8*)&Xt[lr + 16 * fn][ks * 32 + lg * 8];
#pragma unroll
    for (int fo = 0; fo < 4; ++fo)
#pragma unroll
      for (int fn = 0; fn < 4; ++fn)
        acc[fo][fn] = __builtin_amdgcn_mfma_f32_16x16x32_f16(aw[fo], bx[fn], acc[fo][fn], 0, 0, 0);
  }

  // epilogue: C layout col n = lane&15, row o = 4*(lane>>4)+reg
#pragma unroll
  for (int fo = 0; fo < 4; ++fo) {
    const int orow = obase + fo * 16 + lg * 4;
    float bz[4];
#pragma unroll
    for (int r = 0; r < 4; ++r) bz[r] = bias[orow + r];
#pragma unroll
    for (int fn = 0; fn < 4; ++fn)
#pragma unroll
      for (int r = 0; r < 4; ++r)
        outp[(size_t)(orow + r) * HW + n0 + 16 * fn + lr] = (f16)(acc[fo][fn][r] + bz[r]);
  }
}

// ---------------------------------------------------------------------------
// Stage 2: attention, 768 threads (12 waves), one block per (b,c).
// blockIdx.x = b*256 + c (fused grid 2048; fallback grid 256 -> b=0 with
// per-batch base pointers). Body identical to R9:
// [K stage + issue aq/vp] B1 [QK^T, softmax, Pf] B2 [Vt write] B3 [PV].
// LDS = KA(76.8K) + Pf(76.8K) = 153.6 KB -> 1 block/CU.
// ---------------------------------------------------------------------------
__global__ __launch_bounds__(768) void attn_kernel(
    const f16* __restrict__ qkv, float* __restrict__ outb) {
  const int c2  = blockIdx.x;
  const int b   = c2 >> 8;
  const int c   = c2 & 255;
  const int tid = threadIdx.x;
  const int l   = tid & 63;
  const int wv  = tid >> 6;          // 0..11  == q-tile index
  const int lr  = l & 15, lg = l >> 4;

  const f16* __restrict__ qb = qkv + (size_t)(b * 3) * TS;
  const f16* __restrict__ q = qb + (size_t)c * HW;
  const f16* __restrict__ k = qb + (size_t)TS + (size_t)c * HW;
  const f16* __restrict__ v = qb + 2 * (size_t)TS + (size_t)c * HW;
  float* __restrict__ outc = outb + (size_t)b * TS + (size_t)c * HW;

  __shared__ f16 KA[192][200];   // phase1: K [g][w]   phase2: V^T [w][g]
  __shared__ f16 Pf[192][200];   // normalized P [h][g]

  const int h0 = wv * 16;

  // ---- T14 issue-early: Q fragments (consumed in QK^T)
  f16x8 aq[6];
#pragma unroll
  for (int ks = 0; ks < 6; ++ks)
    aq[ks] = *(const f16x8*)(q + (h0 + lr) * 192 + ks * 32 + lg * 8);

  // ---- T14 issue-early: scattered V-gather into regs (written to LDS later)
  const int gA = (tid % 24) * 8, wA = (tid / 24) * 4;   // job A: all threads
  const int jB = tid + 768;                              // job B: tid < 384
  const int gB = (jB % 24) * 8, wB = (jB / 24) * 4;
  uint2 vpA[8], vpB[8];
#pragma unroll
  for (int j = 0; j < 8; ++j) vpA[j] = *(const uint2*)(v + (gA + j) * 192 + wA);
  if (tid < 384) {
#pragma unroll
    for (int j = 0; j < 8; ++j) vpB[j] = *(const uint2*)(v + (gB + j) * 192 + wB);
  }

  // ---- stage K -> KA (16B chunks, coalesced; 4608 = 768*6)
#pragma unroll
  for (int jj = 0; jj < 6; ++jj) {
    int id = tid + jj * 768;
    int g = id / 24, wo = id % 24;
    *(f16x8*)&KA[g][wo * 8] = *(const f16x8*)(k + g * 192 + wo * 8);
  }
  __syncthreads();                              // B1: K visible

  {
    f32x4 S[12];
#pragma unroll
    for (int fg = 0; fg < 12; ++fg) S[fg] = (f32x4){0.f, 0.f, 0.f, 0.f};
#pragma unroll
    for (int ks = 0; ks < 6; ++ks)
#pragma unroll
      for (int fg = 0; fg < 12; ++fg) {
        f16x8 bk_ = *(const f16x8*)&KA[16 * fg + lr][ks * 32 + lg * 8];
        S[fg] = __builtin_amdgcn_mfma_f32_16x16x32_f16(aq[ks], bk_, S[fg], 0, 0, 0);
      }

    // exact softmax per row (row = 4*lg + r; 16 lanes lr hold g-chunks),
    // normalize, store to Pf in [h][g] layout (C-layout-native scatter).
#pragma unroll
    for (int r = 0; r < 4; ++r) {
      float m = S[0][r];
#pragma unroll
      for (int fg = 1; fg < 12; ++fg) m = fmaxf(m, S[fg][r]);
      m = fmaxf(m, __shfl_xor(m, 1));
      m = fmaxf(m, __shfl_xor(m, 2));
      m = fmaxf(m, __shfl_xor(m, 4));
      m = fmaxf(m, __shfl_xor(m, 8));
      float s = 0.f;
#pragma unroll
      for (int fg = 0; fg < 12; ++fg) {
        float e = __expf(S[fg][r] - m);
        S[fg][r] = e;
        s += e;
      }
      s += __shfl_xor(s, 1);
      s += __shfl_xor(s, 2);
      s += __shfl_xor(s, 4);
      s += __shfl_xor(s, 8);
      float rs = 1.f / s;
#pragma unroll
      for (int fg = 0; fg < 12; ++fg)
        Pf[h0 + lg * 4 + r][16 * fg + lr] = (f16)(S[fg][r] * rs);
    }
  }
  __syncthreads();                              // B2: all KA reads done

  // ---- write V^T into KA from the preloaded regs (conflict-free b128 rows)
  {
#pragma unroll
    for (int qd = 0; qd < 4; ++qd) {
      union { unsigned short s[8]; f16x8 vec; } u;
#pragma unroll
      for (int j = 0; j < 8; ++j) u.s[j] = ((const unsigned short*)&vpA[j])[qd];
      *(f16x8*)&KA[wA + qd][gA] = u.vec;
    }
    if (tid < 384) {
#pragma unroll
      for (int qd = 0; qd < 4; ++qd) {
        union { unsigned short s[8]; f16x8 vec; } u;
#pragma unroll
        for (int j = 0; j < 8; ++j) u.s[j] = ((const unsigned short*)&vpB[j])[qd];
        *(f16x8*)&KA[wB + qd][gB] = u.vec;
      }
    }
  }
  __syncthreads();                              // B3: V^T visible

  {
    f32x4 O[12];
#pragma unroll
    for (int fn = 0; fn < 12; ++fn) O[fn] = (f32x4){0.f, 0.f, 0.f, 0.f};

#pragma unroll
    for (int ks = 0; ks < 6; ++ks) {
      f16x8 pa = *(const f16x8*)&Pf[h0 + lr][ks * 32 + lg * 8];  // A: row h, k = g
#pragma unroll
      for (int fn = 0; fn < 12; ++fn) {
        f16x8 bv_ = *(const f16x8*)&KA[16 * fn + lr][ks * 32 + lg * 8];  // B: col w, k = g
        O[fn] = __builtin_amdgcn_mfma_f32_16x16x32_f16(pa, bv_, O[fn], 0, 0, 0);
      }
    }

#pragma unroll
    for (int fn = 0; fn < 12; ++fn)
#pragma unroll
      for (int r = 0; r < 4; ++r)
        outc[(size_t)(h0 + lg * 4 + r) * 192 + 16 * fn + lr] = O[fn][r];
  }
}

// ---------------------------------------------------------------------------
extern "C" void kernel_launch(void* const* d_in, const int* in_sizes, int n_in,
                              void* d_out, int out_size, void* d_ws, size_t ws_size,
                              hipStream_t stream) {
  const float* query = (const float*)d_in[0];
  const float* key_  = (const float*)d_in[1];
  const float* value = (const float*)d_in[2];
  const float* Wq    = (const float*)d_in[3];
  const float* bq    = (const float*)d_in[4];
  const float* Wk    = (const float*)d_in[5];
  const float* bk    = (const float*)d_in[6];
  const float* Wv    = (const float*)d_in[7];
  const float* bv    = (const float*)d_in[8];
  float* out = (float*)d_out;

  f16* wp  = (f16*)d_ws;                        // 3*65536 fp16 = 384 KB
  f16* qkv = (f16*)((char*)d_ws + 524288);

  convert_w_kernel<<<256, 256, 0, stream>>>(Wq, Wk, Wv, wp);

  const size_t need_fused = 524288 + (size_t)8 * 3 * TS * 2;  // ~453.5 MB
  if (ws_size >= need_fused) {
    // Fused: all 8 batches in one conv dispatch + one attn dispatch.
    conv1x1_kernel<<<dim3(576 * 8, 3), 256, 0, stream>>>(
        query, key_, value, wp, bq, bk, bv, qkv);
    attn_kernel<<<2048, 768, 0, stream>>>(qkv, out);
  } else {
    // Fallback: per-batch loop (qkv holds 3 planes = 56.6 MB, reused).
    for (int b = 0; b < 8; ++b) {
      const size_t off = (size_t)b * TS;
      conv1x1_kernel<<<dim3(576, 3), 256, 0, stream>>>(
          query + off, key_ + off, value + off, wp, bq, bk, bv, qkv);
      attn_kernel<<<256, 768, 0, stream>>>(qkv, out + off);
    }
  }
}

// Round 11
// 646.226 us; speedup vs baseline: 1.2281x; 1.0983x over previous
//
#include <hip/hip_runtime.h>
#include <hip/hip_bf16.h>

typedef _Float16 f16;
typedef f16   f16x8 __attribute__((ext_vector_type(8)));
typedef float f32x4 __attribute__((ext_vector_type(4)));

#define HW 36864      /* 192*192 */
#define TS 9437184    /* 256*36864 : per-plane per-batch elements */

// ---------------------------------------------------------------------------
// Pre-kernel: W (fp32 256x256) -> 3 fp16 planes: Wq, Wk, Wv
// ---------------------------------------------------------------------------
__global__ __launch_bounds__(256) void convert_w_kernel(
    const float* __restrict__ wq, const float* __restrict__ wk,
    const float* __restrict__ wv, f16* __restrict__ wp) {
  int i = blockIdx.x * 256 + threadIdx.x;  // 0 .. 65535
  wp[i]             = (f16)wq[i];
  wp[65536 + i]     = (f16)wk[i];
  wp[2 * 65536 + i] = (f16)wv[i];
}

// ---------------------------------------------------------------------------
// Stage 1: 1x1 conv GEMM  out[o,n] = sum_i W[o,i] x[i,n] + b[o]
// R10 post-mortem: conv was 530us (75% of total) with HBM 21% / MfmaUtil 9% /
// Occ 30% -> latency-bound on 64 scalar fp32 loads/thread + 8-way LDS write
// conflicts (7.1M). Rebuilt staging:
//  - float4 loads, 4x4 micro-tile register transpose (16 dwordx4/thread).
//  - X^T tile XOR-swizzled (byte ^= (n&7)<<4 within 512B row, no pad):
//    MFMA b128 reads conflict-free, b64 writes ~4-way. LDS 32KB -> 4 blk/CU.
// grid = (576*NB, 3), block = 256, __launch_bounds__(256,4): VGPR cap 128.
// ---------------------------------------------------------------------------
__global__ __launch_bounds__(256, 4) void conv1x1_kernel(
    const float* __restrict__ xq, const float* __restrict__ xk, const float* __restrict__ xv,
    const f16* __restrict__ wp,
    const float* __restrict__ bq, const float* __restrict__ bk, const float* __restrict__ bv,
    f16* __restrict__ qkv) {
  const int t  = blockIdx.y;
  const int b  = blockIdx.x / 576;
  const int nb = blockIdx.x % 576;
  const float* __restrict__ in   = ((t == 0) ? xq : (t == 1 ? xk : xv)) + (size_t)b * TS;
  const float* __restrict__ bias = (t == 0) ? bq : (t == 1 ? bk : bv);
  const f16* __restrict__ W = wp + t * 65536;
  f16* __restrict__ outp    = qkv + (size_t)(b * 3 + t) * TS;

  const int n0  = nb * 64;
  const int tid = threadIdx.x;
  const int l   = tid & 63;
  const int wv  = tid >> 6;
  const int lr  = l & 15, lg = l >> 4;

  // X^T tile, swizzled: LDS row n (0..63, spatial col), 512B = 256 f16 (i dim).
  // element (i, n) lives at byte n*512 + ((i*2) ^ ((n&7)<<4))  [16B-chunk XOR]
  __shared__ __align__(16) char Xraw[32768];

  // ---- stage: 1024 4x4 micro-tiles, 4 jobs/thread, float4 loads
#pragma unroll
  for (int jj = 0; jj < 4; ++jj) {
    const int jid = jj * 256 + tid;
    const int i0 = (jid >> 4) << 2;      // channel row block (0..252)
    const int c0 = (jid & 15) << 2;      // spatial col block (0..60)
    float4 rv[4];
#pragma unroll
    for (int j = 0; j < 4; ++j)
      rv[j] = *(const float4*)(in + (size_t)(i0 + j) * HW + n0 + c0);
#pragma unroll
    for (int d = 0; d < 4; ++d) {
      const int n = c0 + d;
      union { f16 h[4]; unsigned long long u; } p;
#pragma unroll
      for (int j = 0; j < 4; ++j) p.h[j] = (f16)((&rv[j].x)[d]);
      *(unsigned long long*)(Xraw + n * 512 + ((i0 * 2) ^ ((n & 7) << 4))) = p.u;
    }
  }
  __syncthreads();

  f32x4 acc[4][4];
#pragma unroll
  for (int fo = 0; fo < 4; ++fo)
#pragma unroll
    for (int fn = 0; fn < 4; ++fn) acc[fo][fn] = (f32x4){0.f, 0.f, 0.f, 0.f};

  const int obase = wv * 64;
#pragma unroll
  for (int ks = 0; ks < 8; ++ks) {
    f16x8 aw[4], bx[4];
#pragma unroll
    for (int fo = 0; fo < 4; ++fo)
      aw[fo] = *(const f16x8*)(W + (obase + fo * 16 + lr) * 256 + ks * 32 + lg * 8);
#pragma unroll
    for (int fn = 0; fn < 4; ++fn) {
      const int n = lr + 16 * fn;
      bx[fn] = *(const f16x8*)(Xraw + n * 512 + (((ks * 32 + lg * 8) * 2) ^ ((n & 7) << 4)));
    }
#pragma unroll
    for (int fo = 0; fo < 4; ++fo)
#pragma unroll
      for (int fn = 0; fn < 4; ++fn)
        acc[fo][fn] = __builtin_amdgcn_mfma_f32_16x16x32_f16(aw[fo], bx[fn], acc[fo][fn], 0, 0, 0);
  }

  // epilogue: C layout col n = lane&15, row o = 4*(lane>>4)+reg
#pragma unroll
  for (int fo = 0; fo < 4; ++fo) {
    const int orow = obase + fo * 16 + lg * 4;
    float bz[4];
#pragma unroll
    for (int r = 0; r < 4; ++r) bz[r] = bias[orow + r];
#pragma unroll
    for (int fn = 0; fn < 4; ++fn)
#pragma unroll
      for (int r = 0; r < 4; ++r)
        outp[(size_t)(orow + r) * HW + n0 + 16 * fn + lr] = (f16)(acc[fo][fn][r] + bz[r]);
  }
}

// ---------------------------------------------------------------------------
// Stage 2: attention, 768 threads (12 waves), one block per (b,c).
// blockIdx.x = b*256 + c. [K stage + issue aq/vp] B1 [QK^T, softmax, Pf]
// B2 [Vt write] B3 [PV]. LDS 153.6 KB -> 1 block/CU. (~21us/block-round,
// minor term after R10 attribution flip.)
// ---------------------------------------------------------------------------
__global__ __launch_bounds__(768) void attn_kernel(
    const f16* __restrict__ qkv, float* __restrict__ outb) {
  const int c2  = blockIdx.x;
  const int b   = c2 >> 8;
  const int c   = c2 & 255;
  const int tid = threadIdx.x;
  const int l   = tid & 63;
  const int wv  = tid >> 6;          // 0..11  == q-tile index
  const int lr  = l & 15, lg = l >> 4;

  const f16* __restrict__ qb = qkv + (size_t)(b * 3) * TS;
  const f16* __restrict__ q = qb + (size_t)c * HW;
  const f16* __restrict__ k = qb + (size_t)TS + (size_t)c * HW;
  const f16* __restrict__ v = qb + 2 * (size_t)TS + (size_t)c * HW;
  float* __restrict__ outc = outb + (size_t)b * TS + (size_t)c * HW;

  __shared__ f16 KA[192][200];   // phase1: K [g][w]   phase2: V^T [w][g]
  __shared__ f16 Pf[192][200];   // normalized P [h][g]

  const int h0 = wv * 16;

  // ---- T14 issue-early: Q fragments (consumed in QK^T)
  f16x8 aq[6];
#pragma unroll
  for (int ks = 0; ks < 6; ++ks)
    aq[ks] = *(const f16x8*)(q + (h0 + lr) * 192 + ks * 32 + lg * 8);

  // ---- T14 issue-early: scattered V-gather into regs (written to LDS later)
  const int gA = (tid % 24) * 8, wA = (tid / 24) * 4;   // job A: all threads
  const int jB = tid + 768;                              // job B: tid < 384
  const int gB = (jB % 24) * 8, wB = (jB / 24) * 4;
  uint2 vpA[8], vpB[8];
#pragma unroll
  for (int j = 0; j < 8; ++j) vpA[j] = *(const uint2*)(v + (gA + j) * 192 + wA);
  if (tid < 384) {
#pragma unroll
    for (int j = 0; j < 8; ++j) vpB[j] = *(const uint2*)(v + (gB + j) * 192 + wB);
  }

  // ---- stage K -> KA (16B chunks, coalesced; 4608 = 768*6)
#pragma unroll
  for (int jj = 0; jj < 6; ++jj) {
    int id = tid + jj * 768;
    int g = id / 24, wo = id % 24;
    *(f16x8*)&KA[g][wo * 8] = *(const f16x8*)(k + g * 192 + wo * 8);
  }
  __syncthreads();                              // B1: K visible

  {
    f32x4 S[12];
#pragma unroll
    for (int fg = 0; fg < 12; ++fg) S[fg] = (f32x4){0.f, 0.f, 0.f, 0.f};
#pragma unroll
    for (int ks = 0; ks < 6; ++ks)
#pragma unroll
      for (int fg = 0; fg < 12; ++fg) {
        f16x8 bk_ = *(const f16x8*)&KA[16 * fg + lr][ks * 32 + lg * 8];
        S[fg] = __builtin_amdgcn_mfma_f32_16x16x32_f16(aq[ks], bk_, S[fg], 0, 0, 0);
      }

    // exact softmax per row (row = 4*lg + r; 16 lanes lr hold g-chunks),
    // normalize, store to Pf in [h][g] layout (C-layout-native scatter).
#pragma unroll
    for (int r = 0; r < 4; ++r) {
      float m = S[0][r];
#pragma unroll
      for (int fg = 1; fg < 12; ++fg) m = fmaxf(m, S[fg][r]);
      m = fmaxf(m, __shfl_xor(m, 1));
      m = fmaxf(m, __shfl_xor(m, 2));
      m = fmaxf(m, __shfl_xor(m, 4));
      m = fmaxf(m, __shfl_xor(m, 8));
      float s = 0.f;
#pragma unroll
      for (int fg = 0; fg < 12; ++fg) {
        float e = __expf(S[fg][r] - m);
        S[fg][r] = e;
        s += e;
      }
      s += __shfl_xor(s, 1);
      s += __shfl_xor(s, 2);
      s += __shfl_xor(s, 4);
      s += __shfl_xor(s, 8);
      float rs = 1.f / s;
#pragma unroll
      for (int fg = 0; fg < 12; ++fg)
        Pf[h0 + lg * 4 + r][16 * fg + lr] = (f16)(S[fg][r] * rs);
    }
  }
  __syncthreads();                              // B2: all KA reads done

  // ---- write V^T into KA from the preloaded regs (conflict-free b128 rows)
  {
#pragma unroll
    for (int qd = 0; qd < 4; ++qd) {
      union { unsigned short s[8]; f16x8 vec; } u;
#pragma unroll
      for (int j = 0; j < 8; ++j) u.s[j] = ((const unsigned short*)&vpA[j])[qd];
      *(f16x8*)&KA[wA + qd][gA] = u.vec;
    }
    if (tid < 384) {
#pragma unroll
      for (int qd = 0; qd < 4; ++qd) {
        union { unsigned short s[8]; f16x8 vec; } u;
#pragma unroll
        for (int j = 0; j < 8; ++j) u.s[j] = ((const unsigned short*)&vpB[j])[qd];
        *(f16x8*)&KA[wB + qd][gB] = u.vec;
      }
    }
  }
  __syncthreads();                              // B3: V^T visible

  {
    f32x4 O[12];
#pragma unroll
    for (int fn = 0; fn < 12; ++fn) O[fn] = (f32x4){0.f, 0.f, 0.f, 0.f};

#pragma unroll
    for (int ks = 0; ks < 6; ++ks) {
      f16x8 pa = *(const f16x8*)&Pf[h0 + lr][ks * 32 + lg * 8];  // A: row h, k = g
#pragma unroll
      for (int fn = 0; fn < 12; ++fn) {
        f16x8 bv_ = *(const f16x8*)&KA[16 * fn + lr][ks * 32 + lg * 8];  // B: col w, k = g
        O[fn] = __builtin_amdgcn_mfma_f32_16x16x32_f16(pa, bv_, O[fn], 0, 0, 0);
      }
    }

#pragma unroll
    for (int fn = 0; fn < 12; ++fn)
#pragma unroll
      for (int r = 0; r < 4; ++r)
        outc[(size_t)(h0 + lg * 4 + r) * 192 + 16 * fn + lr] = O[fn][r];
  }
}

// ---------------------------------------------------------------------------
extern "C" void kernel_launch(void* const* d_in, const int* in_sizes, int n_in,
                              void* d_out, int out_size, void* d_ws, size_t ws_size,
                              hipStream_t stream) {
  const float* query = (const float*)d_in[0];
  const float* key_  = (const float*)d_in[1];
  const float* value = (const float*)d_in[2];
  const float* Wq    = (const float*)d_in[3];
  const float* bq    = (const float*)d_in[4];
  const float* Wk    = (const float*)d_in[5];
  const float* bk    = (const float*)d_in[6];
  const float* Wv    = (const float*)d_in[7];
  const float* bv    = (const float*)d_in[8];
  float* out = (float*)d_out;

  f16* wp  = (f16*)d_ws;                        // 3*65536 fp16 = 384 KB
  f16* qkv = (f16*)((char*)d_ws + 524288);

  convert_w_kernel<<<256, 256, 0, stream>>>(Wq, Wk, Wv, wp);

  const size_t need_fused = 524288 + (size_t)8 * 3 * TS * 2;  // ~453.5 MB
  if (ws_size >= need_fused) {
    // Fused: all 8 batches in one conv dispatch + one attn dispatch.
    conv1x1_kernel<<<dim3(576 * 8, 3), 256, 0, stream>>>(
        query, key_, value, wp, bq, bk, bv, qkv);
    attn_kernel<<<2048, 768, 0, stream>>>(qkv, out);
  } else {
    // Fallback: per-batch loop (qkv holds 3 planes = 56.6 MB, reused).
    for (int b = 0; b < 8; ++b) {
      const size_t off = (size_t)b * TS;
      conv1x1_kernel<<<dim3(576, 3), 256, 0, stream>>>(
          query + off, key_ + off, value + off, wp, bq, bk, bv, qkv);
      attn_kernel<<<256, 768, 0, stream>>>(qkv, out + off);
    }
  }
}